// Round 13
// baseline (3525.529 us; speedup 1.0000x reference)
//
#include <hip/hip_runtime.h>

#define T_STEPS 4096
#define BATCH   64
#define NB      16            // batch elements per block
#define INDIM   4
#define H       256
#define OUTD    2
#define CHUNK   32

typedef __fp16 v8h   __attribute__((ext_vector_type(8)));
typedef float  f32x4 __attribute__((ext_vector_type(4)));

__device__ __forceinline__ unsigned int pk(float a, float b) {
    return __builtin_bit_cast(unsigned int, __builtin_amdgcn_cvt_pkrtz(a, b));
}

__device__ __forceinline__ float fast_tanh(float x) {
    float ax = fabsf(x);
    float e  = __expf(-2.0f * ax);
    float r  = (1.0f - e) * __builtin_amdgcn_rcpf(1.0f + e);
    return copysignf(r, x);
}

// 256 threads = 4 waves = 1 wave/SIMD; waves_per_eu(1,1) -> 512-reg budget.
// Per block: 16-batch GEMM recurrence H_new = tanh(Wh*H + [Wi|bias]*[x;1])
// via mfma_f32_16x16x32_f16. Wh lives in registers as A-fragments (144
// dwords, pinned). h round-trips LDS in exact B-fragment order.
__global__ __attribute__((amdgpu_waves_per_eu(1, 1))) __launch_bounds__(256)
void elman_kernel(const float* __restrict__ input,
                  const float* __restrict__ Wi,
                  const float* __restrict__ bi,
                  const float* __restrict__ Wh,
                  const float* __restrict__ bh,
                  const float* __restrict__ Wf,
                  const float* __restrict__ bf,
                  float* __restrict__ out)
{
    const int b0 = blockIdx.x * NB;
    const int t  = threadIdx.x;
    const int w  = t >> 6;          // wave: M rows 64w..64w+63
    const int l  = t & 63;
    const int qD = l >> 4;          // quad
    const int n  = l & 15;          // batch col (B/D col = lane&15)
    const int is_q0 = (qD == 0);

    __shared__ uint4 Bb[2][8][64];      // h as B-fragments, ping-pong (16 KB)
    __shared__ uint2 Xs[CHUNK][16];     // staged x, f16 [i][n][4] (4 KB)
    __shared__ float Hp[2][32][4];      // head partials [buf][o*16+n][w] (1 KB)
    __shared__ float Obx[CHUNK][32];    // finalized outputs (4 KB)
    __shared__ float Dump[64];

    // ---- A fragments: Wh rows (+ 9th kstep = [Wi | bias]) in registers ----
    // A layout (verified m120): m = lane&15, k = quad*8 + j  (j = elem 0..7)
    uint4 Afu[4][9];
    #pragma unroll
    for (int s = 0; s < 4; ++s) {
        const int m = 64 * w + 16 * s + n;
        #pragma unroll
        for (int kk = 0; kk < 8; ++kk) {
            const float* ap = Wh + (size_t)m * H + kk * 32 + qD * 8;
            float4 u0 = *(const float4*)ap;
            float4 u1 = *(const float4*)(ap + 4);
            Afu[s][kk].x = pk(u0.x, u0.y);
            Afu[s][kk].y = pk(u0.z, u0.w);
            Afu[s][kk].z = pk(u1.x, u1.y);
            Afu[s][kk].w = pk(u1.z, u1.w);
        }
        if (is_q0) {
            float4 wiv  = *(const float4*)(Wi + m * INDIM);
            float  bias = bi[m] + bh[m];
            Afu[s][8].x = pk(wiv.x, wiv.y);
            Afu[s][8].y = pk(wiv.z, wiv.w);
            Afu[s][8].z = pk(bias, 0.0f);
            Afu[s][8].w = 0u;
        } else {
            Afu[s][8] = make_uint4(0u, 0u, 0u, 0u);
        }
    }
    #pragma unroll
    for (int s = 0; s < 4; ++s)
        #pragma unroll
        for (int kk = 0; kk < 9; ++kk)
            asm volatile("" : "+v"(Afu[s][kk].x), "+v"(Afu[s][kk].y),
                               "+v"(Afu[s][kk].z), "+v"(Afu[s][kk].w));

    // head weights for my 16 rows (k = 64w + 16s + 4qD + r)
    float wf0[16], wf1[16];
    #pragma unroll
    for (int s = 0; s < 4; ++s)
        #pragma unroll
        for (int r = 0; r < 4; ++r) {
            const int k = 64 * w + 16 * s + 4 * qD + r;
            wf0[s * 4 + r] = Wf[k];
            wf1[s * 4 + r] = Wf[H + k];
        }
    const float bf0 = bf[0], bf1 = bf[1];

    for (int idx = t; idx < 1024; idx += 256)      // h0 = 0 (both buffers)
        ((uint4*)Bb)[idx] = make_uint4(0u, 0u, 0u, 0u);
    __syncthreads();

    for (int chunk = 0; chunk < T_STEPS / CHUNK; ++chunk) {
        // ---- stage this chunk's x as f16 ----
        for (int idx = t; idx < CHUNK * 16; idx += 256) {
            const int i = idx >> 4, nn = idx & 15;
            const int ta = chunk * CHUNK + i;
            float4 xv = *(const float4*)(input + ((size_t)ta * BATCH + b0 + nn) * INDIM);
            Xs[i][nn] = make_uint2(pk(xv.x, xv.y), pk(xv.z, xv.w));
        }
        __syncthreads();

        #pragma unroll 1
        for (int i = 0; i < CHUNK; ++i) {
            const int step = chunk * CHUNK + i;
            const int rb = step & 1, wb = rb ^ 1;

            // wave0: finalize previous step's output (within-chunk)
            if (w == 0 && l < 32 && i > 0) {
                f32x4 h4 = *(const f32x4*)&Hp[wb][l][0];
                float o  = h4.x + h4.y + h4.z + h4.w + ((l >> 4) ? bf1 : bf0);
                Obx[i - 1][l] = fast_tanh(o);
            }

            // B fragments of h (k = kst*32 + quad*8 + j on lane = self)
            uint4 bfu[8];
            #pragma unroll
            for (int kk = 0; kk < 8; ++kk) bfu[kk] = Bb[rb][kk][l];
            // 9th kstep: [x_t ; 1] built in registers
            uint2 xr = Xs[i][n];
            uint4 b9u;
            b9u.x = is_q0 ? xr.x : 0u;
            b9u.y = is_q0 ? xr.y : 0u;
            b9u.z = is_q0 ? 0x00003C00u : 0u;   // f16 1.0 at element 4
            b9u.w = 0u;

            f32x4 acc[4];
            {
                v8h b9 = __builtin_bit_cast(v8h, b9u);
                f32x4 z = {0.f, 0.f, 0.f, 0.f};
                #pragma unroll
                for (int s = 0; s < 4; ++s)
                    acc[s] = __builtin_amdgcn_mfma_f32_16x16x32_f16(
                        __builtin_bit_cast(v8h, Afu[s][8]), b9, z, 0, 0, 0);
            }
            #pragma unroll
            for (int kk = 0; kk < 8; ++kk) {
                v8h bk = __builtin_bit_cast(v8h, bfu[kk]);
                #pragma unroll
                for (int s = 0; s < 4; ++s)
                    acc[s] = __builtin_amdgcn_mfma_f32_16x16x32_f16(
                        __builtin_bit_cast(v8h, Afu[s][kk]), bk, acc[s], 0, 0, 0);
            }

            // tanh (D layout m89: row = quad*4 + r, col = n)
            float hf[4][4];
            #pragma unroll
            for (int s = 0; s < 4; ++s)
                #pragma unroll
                for (int r = 0; r < 4; ++r)
                    hf[s][r] = fast_tanh(acc[s][r]);

            // write h_new as next step's B-fragments (one b64 per subtile)
            #pragma unroll
            for (int s = 0; s < 4; ++s) {
                const int kst = 2 * w + (s >> 1);
                const int q   = 2 * (s & 1) + (qD >> 1);
                uint2* bw = (uint2*)&Bb[wb][kst][q * 16 + n];
                bw[qD & 1] = make_uint2(pk(hf[s][0], hf[s][1]),
                                        pk(hf[s][2], hf[s][3]));
            }

            // head partials (uses f32 h, pre-quantization)
            float p0 = 0.f, p1 = 0.f;
            #pragma unroll
            for (int s = 0; s < 4; ++s)
                #pragma unroll
                for (int r = 0; r < 4; ++r) {
                    p0 = fmaf(wf0[s * 4 + r], hf[s][r], p0);
                    p1 = fmaf(wf1[s * 4 + r], hf[s][r], p1);
                }
            p0 += __shfl_xor(p0, 16, 64);  p0 += __shfl_xor(p0, 32, 64);
            p1 += __shfl_xor(p1, 16, 64);  p1 += __shfl_xor(p1, 32, 64);
            float* h0a = is_q0 ? &Hp[rb][n][w]      : &Dump[l];
            float* h1a = is_q0 ? &Hp[rb][16 + n][w] : &Dump[l];
            *h0a = p0;
            *h1a = p1;

            __syncthreads();
        }

        // finalize step 31 (its Hp buffer parity: (chunk*32+31)&1 == 1)
        if (w == 0 && l < 32) {
            f32x4 h4 = *(const f32x4*)&Hp[1][l][0];
            float o  = h4.x + h4.y + h4.z + h4.w + ((l >> 4) ? bf1 : bf0);
            Obx[CHUNK - 1][l] = fast_tanh(o);
        }
        __syncthreads();

        // flush outputs: element c = n*2+o -> Obx col on = (c&1)*16 + (c>>1)
        for (int e = t; e < CHUNK * 32; e += 256) {
            const int i = e >> 5, c = e & 31;
            const int on = (c & 1) * 16 + (c >> 1);
            out[(size_t)(chunk * CHUNK + i) * BATCH * OUTD + b0 * OUTD + c] =
                Obx[i][on];
        }
    }
}

extern "C" void kernel_launch(void* const* d_in, const int* in_sizes, int n_in,
                              void* d_out, int out_size, void* d_ws, size_t ws_size,
                              hipStream_t stream) {
    const float* input = (const float*)d_in[0];
    // d_in[1] = target (unused by forward)
    const float* Wi = (const float*)d_in[2];
    const float* bi = (const float*)d_in[3];
    const float* Wh = (const float*)d_in[4];
    const float* bh = (const float*)d_in[5];
    const float* Wf = (const float*)d_in[6];
    const float* bf = (const float*)d_in[7];
    float* out = (float*)d_out;

    elman_kernel<<<dim3(BATCH / NB), dim3(256), 0, stream>>>(
        input, Wi, bi, Wh, bh, Wf, bf, out);
}